// Round 8
// baseline (354.529 us; speedup 1.0000x reference)
//
#include <hip/hip_runtime.h>
#include <hip/hip_bf16.h>
#include <hip/hip_fp8.h>

#define B_N 4096
#define D_K 2048

typedef __attribute__((ext_vector_type(4))) int   i32x4;
typedef __attribute__((ext_vector_type(8))) int   i32x8;
typedef __attribute__((ext_vector_type(4))) float f32x4;

__device__ __forceinline__ void gl_lds16(const void* g, void* l) {
    __builtin_amdgcn_global_load_lds(
        (const __attribute__((address_space(1))) unsigned int*)g,
        (__attribute__((address_space(3))) unsigned int*)l,
        16, 0, 0);
}

// ---------------- Kernel 1: row L2-normalize -> fp8 e4m3 (prescaled by 32) ----------------
__global__ __launch_bounds__(256) void knorm3(const float* __restrict__ C,
                                              const float* __restrict__ S,
                                              unsigned char* __restrict__ Cq,
                                              unsigned char* __restrict__ Sq) {
    int b = blockIdx.x;            // 0..8191
    const float* X;
    unsigned char* Y;
    if (b < B_N) { X = C + (size_t)b * D_K; Y = Cq + (size_t)b * D_K; }
    else         { X = S + (size_t)(b - B_N) * D_K; Y = Sq + (size_t)(b - B_N) * D_K; }
    int tid = threadIdx.x;

    float4 v0 = ((const float4*)X)[tid * 2];
    float4 v1 = ((const float4*)X)[tid * 2 + 1];
    float ss = v0.x*v0.x + v0.y*v0.y + v0.z*v0.z + v0.w*v0.w
             + v1.x*v1.x + v1.y*v1.y + v1.z*v1.z + v1.w*v1.w;
    #pragma unroll
    for (int off = 1; off < 64; off <<= 1) ss += __shfl_xor(ss, off, 64);
    __shared__ float wsum[4];
    if ((tid & 63) == 0) wsum[tid >> 6] = ss;
    __syncthreads();
    float tot = wsum[0] + wsum[1] + wsum[2] + wsum[3];
    // prescale by 32: elements ~N(0,1/D) land in e4m3's sweet spot; epilogue divides by 1024
    float inv = 32.f / fmaxf(sqrtf(tot), 1e-12f);

    float vals[8] = { v0.x, v0.y, v0.z, v0.w, v1.x, v1.y, v1.z, v1.w };
    union { unsigned char b8[8]; unsigned long long u; } o;
    #pragma unroll
    for (int j = 0; j < 8; ++j) {
        __hip_fp8_e4m3 q(vals[j] * inv);   // OCP e4m3, RNE + satfinite
        o.b8[j] = q.__x;
    }
    *(unsigned long long*)(Y + tid * 8) = o.u;
}

// ---------------- Kernel 2: 128x128 MX-fp8 GEMM (m97 structure) + fused InfoNCE epilogue ----------------
// BK=128 (one mfma_scale_f32_16x16x128_f8f6f4 per acc per K-step, unit scales).
// LDS 32 KB single-buffered, linear [128 rows][128 B]; 16B-chunk XOR-swizzle by (row&7)
// realized as pre-swizzled global source (gl_lds linear dest) + swizzled ds_read.
// 4 waves (2x2), wave tile 64x64, 4x4 fragments, 16 MFMA + 16 ds_read_b128 per K-step.

#define QBK 128
#define QNT (D_K / QBK)   /* 16 */

__global__ __launch_bounds__(256) void kgemm_q8(const unsigned char* __restrict__ Aq,
                                                const unsigned char* __restrict__ Bq,
                                                const float* __restrict__ temp,
                                                float* __restrict__ rowsum,
                                                float* __restrict__ colsum,
                                                float* __restrict__ diag) {
    __shared__ __align__(16) unsigned char As[128 * 128];   // 16 KB
    __shared__ __align__(16) unsigned char Bs[128 * 128];   // 16 KB

    const int tid  = threadIdx.x;
    const int lane = tid & 63;
    const int wid  = tid >> 6;
    const int wr   = wid >> 1;     // 0..1
    const int wc   = wid & 1;      // 0..1
    const int brow = blockIdx.x * 128;
    const int bcol = blockIdx.y * 128;

    // ---- staging: thread t stages rows {t>>3 + 32i}, fixed swizzled k-chunk ----
    const int srow = tid >> 3;                               // 0..31
    const int sch  = ((tid & 7) ^ (srow & 7)) * 16;          // pre-swizzled source k-byte
    const unsigned char* gA = Aq + (size_t)(brow + srow) * D_K + sch;
    const unsigned char* gB = Bq + (size_t)(bcol + srow) * D_K + sch;

    // ---- ds_read constants (swizzled): fragment = 32 consecutive k-bytes = chunks 2kq,2kq+1 ----
    const int lrow = lane & 15;
    const int kq   = lane >> 4;                              // 0..3
    const int sw   = lrow & 7;
    const int c0   = ((2 * kq)     ^ sw) * 16;
    const int c1   = ((2 * kq + 1) ^ sw) * 16;
    const int abase = (wr * 64 + lrow) * 128;                // + m*16*128
    const int bbase = (wc * 64 + lrow) * 128;

    f32x4 acc[4][4];
    #pragma unroll
    for (int m = 0; m < 4; ++m)
        #pragma unroll
        for (int n = 0; n < 4; ++n) acc[m][n] = (f32x4){0.f, 0.f, 0.f, 0.f};

    for (int k0 = 0; k0 < D_K; k0 += QBK) {
        #pragma unroll
        for (int i = 0; i < 4; ++i) {
            gl_lds16(gA + k0 + (size_t)(32 * i) * D_K, As + tid * 16 + i * 4096);
            gl_lds16(gB + k0 + (size_t)(32 * i) * D_K, Bs + tid * 16 + i * 4096);
        }
        __syncthreads();   // compiler drains vmcnt before barrier

        i32x8 a8[4], b8[4];
        #pragma unroll
        for (int m = 0; m < 4; ++m) {
            i32x4 lo = *(const i32x4*)(As + abase + m * 2048 + c0);
            i32x4 hi = *(const i32x4*)(As + abase + m * 2048 + c1);
            a8[m] = (i32x8){lo[0], lo[1], lo[2], lo[3], hi[0], hi[1], hi[2], hi[3]};
        }
        #pragma unroll
        for (int n = 0; n < 4; ++n) {
            i32x4 lo = *(const i32x4*)(Bs + bbase + n * 2048 + c0);
            i32x4 hi = *(const i32x4*)(Bs + bbase + n * 2048 + c1);
            b8[n] = (i32x8){lo[0], lo[1], lo[2], lo[3], hi[0], hi[1], hi[2], hi[3]};
        }

        #pragma unroll
        for (int m = 0; m < 4; ++m)
            #pragma unroll
            for (int n = 0; n < 4; ++n)
                acc[m][n] = __builtin_amdgcn_mfma_scale_f32_16x16x128_f8f6f4(
                    a8[m], b8[n], acc[m][n],
                    0 /*cbsz: fp8 e4m3*/, 0 /*blgp: fp8 e4m3*/,
                    0, 127 /*scaleA = 2^0*/, 0, 127 /*scaleB = 2^0*/);
        __syncthreads();
    }

    // ------- epilogue: sim = acc/1024; relu*e^t, shifted exp, row/col sums, diag -------
    const float scl = expf(temp[0]);
    const int rbase = brow + wr * 64;
    const int cbase = bcol + wc * 64 + lrow;
    const int rj = kq * 4;

    float rs[4][4];
    float cs[4];
    #pragma unroll
    for (int m = 0; m < 4; ++m)
        #pragma unroll
        for (int j = 0; j < 4; ++j) rs[m][j] = 0.f;
    #pragma unroll
    for (int n = 0; n < 4; ++n) cs[n] = 0.f;

    #pragma unroll
    for (int m = 0; m < 4; ++m) {
        #pragma unroll
        for (int n = 0; n < 4; ++n) {
            #pragma unroll
            for (int j = 0; j < 4; ++j) {
                float sim = acc[m][n][j] * (1.f / 1024.f);   // undo 32x32 prescale
                float v = fmaxf(sim, 0.f) * scl;
                int gr = rbase + m * 16 + rj + j;
                int gc = cbase + n * 16;
                if (gr == gc) diag[gr] = v;
                float p = expf(v - scl);
                rs[m][j] += p;
                cs[n]    += p;
            }
        }
    }

    #pragma unroll
    for (int m = 0; m < 4; ++m) {
        #pragma unroll
        for (int j = 0; j < 4; ++j) {
            float v = rs[m][j];
            v += __shfl_xor(v, 1, 64);
            v += __shfl_xor(v, 2, 64);
            v += __shfl_xor(v, 4, 64);
            v += __shfl_xor(v, 8, 64);
            if (lrow == 0) atomicAdd(&rowsum[rbase + m * 16 + rj + j], v);
        }
    }
    #pragma unroll
    for (int n = 0; n < 4; ++n) {
        float v = cs[n];
        v += __shfl_xor(v, 16, 64);
        v += __shfl_xor(v, 32, 64);
        if (kq == 0) atomicAdd(&colsum[cbase + n * 16], v);
    }
}

// ---------------- Kernel 3: final reduction to scalar loss ----------------
__global__ __launch_bounds__(256) void kfinal(const float* __restrict__ rowsum,
                                              const float* __restrict__ colsum,
                                              const float* __restrict__ diag,
                                              const float* __restrict__ temp,
                                              float* __restrict__ out) {
    int tid = threadIdx.x;
    float M = expf(temp[0]);
    float acc = 0.f;
    for (int i = tid; i < B_N; i += 256) {
        acc += logf(rowsum[i]) + logf(colsum[i]) + 2.f * M - 2.f * diag[i];
    }
    #pragma unroll
    for (int off = 1; off < 64; off <<= 1) acc += __shfl_xor(acc, off, 64);
    __shared__ float wsum[4];
    if ((tid & 63) == 0) wsum[tid >> 6] = acc;
    __syncthreads();
    if (tid == 0) {
        float t = wsum[0] + wsum[1] + wsum[2] + wsum[3];
        out[0] = t * (0.5f / (float)B_N);
    }
}

extern "C" void kernel_launch(void* const* d_in, const int* in_sizes, int n_in,
                              void* d_out, int out_size, void* d_ws, size_t ws_size,
                              hipStream_t stream) {
    const float* Cf   = (const float*)d_in[0];
    const float* Sf   = (const float*)d_in[1];
    const float* temp = (const float*)d_in[2];

    const size_t MATEL = (size_t)B_N * D_K;                // 8M elems
    unsigned char* Cq = (unsigned char*)d_ws;              // 8 MB
    unsigned char* Sq = Cq + MATEL;                        // 8 MB
    float* rowsum = (float*)(Sq + MATEL);                  // 16 KB
    float* colsum = rowsum + B_N;
    float* diag   = colsum + B_N;

    hipMemsetAsync(rowsum, 0, 2 * B_N * sizeof(float), stream);
    knorm3<<<2 * B_N, 256, 0, stream>>>(Cf, Sf, Cq, Sq);
    dim3 grid(B_N / 128, B_N / 128);
    kgemm_q8<<<grid, 256, 0, stream>>>(Cq, Sq, temp, rowsum, colsum, diag);
    kfinal<<<1, 256, 0, stream>>>(rowsum, colsum, diag, temp, (float*)d_out);
}

// Round 9
// 82.776 us; speedup vs baseline: 4.2830x; 4.2830x over previous
//
#include <hip/hip_runtime.h>
#include <hip/hip_bf16.h>
#include <hip/hip_fp8.h>

#define B_N 4096
#define D_K 2048

typedef __attribute__((ext_vector_type(4))) int   i32x4;
typedef __attribute__((ext_vector_type(8))) int   i32x8;
typedef __attribute__((ext_vector_type(4))) float f32x4;

union U8 { struct { i32x4 lo, hi; } h; i32x8 v; };

__device__ __forceinline__ void gl_lds16(const void* g, void* l) {
    __builtin_amdgcn_global_load_lds(
        (const __attribute__((address_space(1))) unsigned int*)g,
        (__attribute__((address_space(3))) unsigned int*)l,
        16, 0, 0);
}

// ---------------- Kernel 1: row L2-normalize -> fp8 e4m3 (prescaled by 32) ----------------
__global__ __launch_bounds__(256) void knorm3(const float* __restrict__ C,
                                              const float* __restrict__ S,
                                              unsigned char* __restrict__ Cq,
                                              unsigned char* __restrict__ Sq) {
    int b = blockIdx.x;            // 0..8191
    const float* X;
    unsigned char* Y;
    if (b < B_N) { X = C + (size_t)b * D_K; Y = Cq + (size_t)b * D_K; }
    else         { X = S + (size_t)(b - B_N) * D_K; Y = Sq + (size_t)(b - B_N) * D_K; }
    int tid = threadIdx.x;

    float4 v0 = ((const float4*)X)[tid * 2];
    float4 v1 = ((const float4*)X)[tid * 2 + 1];
    float ss = v0.x*v0.x + v0.y*v0.y + v0.z*v0.z + v0.w*v0.w
             + v1.x*v1.x + v1.y*v1.y + v1.z*v1.z + v1.w*v1.w;
    #pragma unroll
    for (int off = 1; off < 64; off <<= 1) ss += __shfl_xor(ss, off, 64);
    __shared__ float wsum[4];
    if ((tid & 63) == 0) wsum[tid >> 6] = ss;
    __syncthreads();
    float tot = wsum[0] + wsum[1] + wsum[2] + wsum[3];
    // prescale by 32: elements ~N(0,1/D) land in e4m3's sweet spot; epilogue divides by 1024
    float inv = 32.f / fmaxf(sqrtf(tot), 1e-12f);

    float vals[8] = { v0.x, v0.y, v0.z, v0.w, v1.x, v1.y, v1.z, v1.w };
    union { unsigned char b8[8]; unsigned long long u; } o;
    #pragma unroll
    for (int j = 0; j < 8; ++j) {
        __hip_fp8_e4m3 q(vals[j] * inv);   // OCP e4m3, RNE + satfinite
        o.b8[j] = q.__x;
    }
    *(unsigned long long*)(Y + tid * 8) = o.u;
}

// ---------------- Kernel 2: 128x128 MX-fp8 GEMM (m97 structure) + fused InfoNCE epilogue ----------------
// BK=128, one mfma_scale_f32_16x16x128_f8f6f4 per acc per K-step, unit scales (e8m0=127).
// LDS 32 KB single-buffered, linear [128 rows][128 B]; 16B-chunk XOR-swizzle by (row&7)
// via pre-swizzled global source (gl_lds linear dest) + swizzled ds_read (verified R8: correct).
// Register-pressure fix vs R8: union-assembled i32x8 (no insert chains); B fragments resident
// (32 regs), A processed one-m-at-a-time with sched_barrier(0) fences -> peak live ~130 VGPR.

#define QBK 128

__global__ __launch_bounds__(256) void kgemm_q8(const unsigned char* __restrict__ Aq,
                                                const unsigned char* __restrict__ Bq,
                                                const float* __restrict__ temp,
                                                float* __restrict__ rowsum,
                                                float* __restrict__ colsum,
                                                float* __restrict__ diag) {
    __shared__ __align__(16) unsigned char As[128 * 128];   // 16 KB
    __shared__ __align__(16) unsigned char Bs[128 * 128];   // 16 KB

    const int tid  = threadIdx.x;
    const int lane = tid & 63;
    const int wid  = tid >> 6;
    const int wr   = wid >> 1;     // 0..1
    const int wc   = wid & 1;      // 0..1
    const int brow = blockIdx.x * 128;
    const int bcol = blockIdx.y * 128;

    // ---- staging: thread t stages rows {t>>3 + 32i}, fixed pre-swizzled k-chunk ----
    const int srow = tid >> 3;                               // 0..31
    const int sch  = ((tid & 7) ^ (srow & 7)) * 16;          // pre-swizzled source k-byte
    const unsigned char* gA = Aq + (size_t)(brow + srow) * D_K + sch;
    const unsigned char* gB = Bq + (size_t)(bcol + srow) * D_K + sch;

    // ---- ds_read constants (swizzled): fragment = logical chunks {2kq, 2kq+1} ----
    const int lrow = lane & 15;
    const int kq   = lane >> 4;                              // 0..3
    const int sw   = lrow & 7;
    const int c0   = ((2 * kq)     ^ sw) * 16;
    const int c1   = ((2 * kq + 1) ^ sw) * 16;
    const int abase = (wr * 64 + lrow) * 128;                // + m*16*128
    const int bbase = (wc * 64 + lrow) * 128;

    f32x4 acc[4][4];
    #pragma unroll
    for (int m = 0; m < 4; ++m)
        #pragma unroll
        for (int n = 0; n < 4; ++n) acc[m][n] = (f32x4){0.f, 0.f, 0.f, 0.f};

    for (int k0 = 0; k0 < D_K; k0 += QBK) {
        #pragma unroll
        for (int i = 0; i < 4; ++i) {
            gl_lds16(gA + k0 + (size_t)(32 * i) * D_K, As + tid * 16 + i * 4096);
            gl_lds16(gB + k0 + (size_t)(32 * i) * D_K, Bs + tid * 16 + i * 4096);
        }
        __syncthreads();   // compiler drains vmcnt before barrier

        // B fragments stay resident (4 x 8 = 32 VGPR)
        U8 b0, b1, b2, b3;
        b0.h.lo = *(const i32x4*)(Bs + bbase + 0 * 2048 + c0);
        b0.h.hi = *(const i32x4*)(Bs + bbase + 0 * 2048 + c1);
        b1.h.lo = *(const i32x4*)(Bs + bbase + 1 * 2048 + c0);
        b1.h.hi = *(const i32x4*)(Bs + bbase + 1 * 2048 + c1);
        b2.h.lo = *(const i32x4*)(Bs + bbase + 2 * 2048 + c0);
        b2.h.hi = *(const i32x4*)(Bs + bbase + 2 * 2048 + c1);
        b3.h.lo = *(const i32x4*)(Bs + bbase + 3 * 2048 + c0);
        b3.h.hi = *(const i32x4*)(Bs + bbase + 3 * 2048 + c1);
        __builtin_amdgcn_sched_barrier(0);

        // A one m at a time; fences stop cross-m hoisting (register-pressure cap)
        #define QMMA(mm) do { \
            U8 a_; \
            a_.h.lo = *(const i32x4*)(As + abase + (mm) * 2048 + c0); \
            a_.h.hi = *(const i32x4*)(As + abase + (mm) * 2048 + c1); \
            acc[mm][0] = __builtin_amdgcn_mfma_scale_f32_16x16x128_f8f6f4( \
                a_.v, b0.v, acc[mm][0], 0, 0, 0, 127, 0, 127); \
            acc[mm][1] = __builtin_amdgcn_mfma_scale_f32_16x16x128_f8f6f4( \
                a_.v, b1.v, acc[mm][1], 0, 0, 0, 127, 0, 127); \
            acc[mm][2] = __builtin_amdgcn_mfma_scale_f32_16x16x128_f8f6f4( \
                a_.v, b2.v, acc[mm][2], 0, 0, 0, 127, 0, 127); \
            acc[mm][3] = __builtin_amdgcn_mfma_scale_f32_16x16x128_f8f6f4( \
                a_.v, b3.v, acc[mm][3], 0, 0, 0, 127, 0, 127); \
            __builtin_amdgcn_sched_barrier(0); \
        } while (0)

        QMMA(0);
        QMMA(1);
        QMMA(2);
        QMMA(3);
        #undef QMMA

        __syncthreads();
    }

    // ------- epilogue: sim = acc/1024; relu*e^t, shifted exp, row/col sums, diag -------
    const float scl = expf(temp[0]);
    const int rbase = brow + wr * 64;
    const int cbase = bcol + wc * 64 + lrow;
    const int rj = kq * 4;

    float rs[4][4];
    float cs[4];
    #pragma unroll
    for (int m = 0; m < 4; ++m)
        #pragma unroll
        for (int j = 0; j < 4; ++j) rs[m][j] = 0.f;
    #pragma unroll
    for (int n = 0; n < 4; ++n) cs[n] = 0.f;

    #pragma unroll
    for (int m = 0; m < 4; ++m) {
        #pragma unroll
        for (int n = 0; n < 4; ++n) {
            #pragma unroll
            for (int j = 0; j < 4; ++j) {
                float sim = acc[m][n][j] * (1.f / 1024.f);   // undo 32x32 prescale
                float v = fmaxf(sim, 0.f) * scl;
                int gr = rbase + m * 16 + rj + j;
                int gc = cbase + n * 16;
                if (gr == gc) diag[gr] = v;
                float p = expf(v - scl);
                rs[m][j] += p;
                cs[n]    += p;
            }
        }
    }

    #pragma unroll
    for (int m = 0; m < 4; ++m) {
        #pragma unroll
        for (int j = 0; j < 4; ++j) {
            float v = rs[m][j];
            v += __shfl_xor(v, 1, 64);
            v += __shfl_xor(v, 2, 64);
            v += __shfl_xor(v, 4, 64);
            v += __shfl_xor(v, 8, 64);
            if (lrow == 0) atomicAdd(&rowsum[rbase + m * 16 + rj + j], v);
        }
    }
    #pragma unroll
    for (int n = 0; n < 4; ++n) {
        float v = cs[n];
        v += __shfl_xor(v, 16, 64);
        v += __shfl_xor(v, 32, 64);
        if (kq == 0) atomicAdd(&colsum[cbase + n * 16], v);
    }
}

// ---------------- Kernel 3: final reduction to scalar loss ----------------
__global__ __launch_bounds__(256) void kfinal(const float* __restrict__ rowsum,
                                              const float* __restrict__ colsum,
                                              const float* __restrict__ diag,
                                              const float* __restrict__ temp,
                                              float* __restrict__ out) {
    int tid = threadIdx.x;
    float M = expf(temp[0]);
    float acc = 0.f;
    for (int i = tid; i < B_N; i += 256) {
        acc += logf(rowsum[i]) + logf(colsum[i]) + 2.f * M - 2.f * diag[i];
    }
    #pragma unroll
    for (int off = 1; off < 64; off <<= 1) acc += __shfl_xor(acc, off, 64);
    __shared__ float wsum[4];
    if ((tid & 63) == 0) wsum[tid >> 6] = acc;
    __syncthreads();
    if (tid == 0) {
        float t = wsum[0] + wsum[1] + wsum[2] + wsum[3];
        out[0] = t * (0.5f / (float)B_N);
    }
}

extern "C" void kernel_launch(void* const* d_in, const int* in_sizes, int n_in,
                              void* d_out, int out_size, void* d_ws, size_t ws_size,
                              hipStream_t stream) {
    const float* Cf   = (const float*)d_in[0];
    const float* Sf   = (const float*)d_in[1];
    const float* temp = (const float*)d_in[2];

    const size_t MATEL = (size_t)B_N * D_K;                // 8M elems
    unsigned char* Cq = (unsigned char*)d_ws;              // 8 MB
    unsigned char* Sq = Cq + MATEL;                        // 8 MB
    float* rowsum = (float*)(Sq + MATEL);                  // 16 KB
    float* colsum = rowsum + B_N;
    float* diag   = colsum + B_N;

    hipMemsetAsync(rowsum, 0, 2 * B_N * sizeof(float), stream);
    knorm3<<<2 * B_N, 256, 0, stream>>>(Cf, Sf, Cq, Sq);
    dim3 grid(B_N / 128, B_N / 128);
    kgemm_q8<<<grid, 256, 0, stream>>>(Cq, Sq, temp, rowsum, colsum, diag);
    kfinal<<<1, 256, 0, stream>>>(rowsum, colsum, diag, temp, (float*)d_out);
}